// Round 9
// baseline (188.011 us; speedup 1.0000x reference)
//
#include <hip/hip_runtime.h>
#include <math.h>

#define B_  2
#define S_  2048
#define E_  1024
#define H_  16
#define HD_ 64
#define N3_ 3072
#define M_  (B_*S_)   // 4096

typedef _Float16 h8  __attribute__((ext_vector_type(8)));
typedef _Float16 h4  __attribute__((ext_vector_type(4)));
typedef _Float16 h2  __attribute__((ext_vector_type(2)));
typedef __fp16   fp16x2 __attribute__((ext_vector_type(2)));
typedef float    f4  __attribute__((ext_vector_type(4)));
typedef float    fv16 __attribute__((ext_vector_type(16)));

typedef __attribute__((address_space(3))) unsigned int       lds_u32;
typedef const __attribute__((address_space(1))) unsigned int glob_u32;

// async global->LDS, 16B/lane; global addr per-lane, LDS dest = base + lane*16.
__device__ __forceinline__ void gld16(const void* g, void* l) {
    __builtin_amdgcn_global_load_lds((glob_u32*)g, (lds_u32*)l, 16, 0, 0);
}
__device__ __forceinline__ float exp2_hw(float x) { return __builtin_amdgcn_exp2f(x); }
__device__ __forceinline__ float fmax3(float a, float b, float c) {
    return fmaxf(fmaxf(a, b), c);     // fuses to v_max3_f32
}
__device__ __forceinline__ h2 cvt_pk_f16(float a, float b) {
    fp16x2 r = __builtin_amdgcn_cvt_pkrtz(a, b);
    return __builtin_bit_cast(h2, r);
}

#define QSCALE 0.18033688011112042f   // log2(e)/8
#define RESCALE_THR 8.0f              // defer-max threshold (log2 domain): P <= 2^8

// ---------------- kernel 0: fused prep ----------------
// blocks [0,2048): x fp32 -> f16 (2048 elems/block)
// blocks [2048,2050): w fp32 -> f16 (2048 elems/block)
// blocks [2050,2818): W [K][N] fp32 -> Wt [N][K] f16 (64x64 tiles)
__global__ __launch_bounds__(256) void prep_kernel(
        const float* __restrict__ x, _Float16* __restrict__ x16,
        const float* __restrict__ w, _Float16* __restrict__ w16,
        const float* __restrict__ W, _Float16* __restrict__ Wt) {
    __shared__ float T[64][65];
    int L = blockIdx.x;
    int tid = threadIdx.x;
    if (L < 2050) {
        const float* src = (L < 2048) ? &x[(size_t)L * 2048] : &w[(size_t)(L - 2048) * 2048];
        _Float16* dst    = (L < 2048) ? &x16[(size_t)L * 2048] : &w16[(size_t)(L - 2048) * 2048];
        int i = tid * 8;
        float4 u = *(const float4*)&src[i];
        float4 v = *(const float4*)&src[i + 4];
        h8 o;
        o[0] = (_Float16)u.x; o[1] = (_Float16)u.y; o[2] = (_Float16)u.z; o[3] = (_Float16)u.w;
        o[4] = (_Float16)v.x; o[5] = (_Float16)v.y; o[6] = (_Float16)v.z; o[7] = (_Float16)v.w;
        *(h8*)&dst[i] = o;
    } else {
        int L2 = L - 2050;
        int k0 = (L2 & 15) * 64, n0 = (L2 >> 4) * 64;
        int r = tid >> 4, c4 = (tid & 15) * 4;
#pragma unroll
        for (int i = 0; i < 4; i++) {
            int row = r + i * 16;
            float4 u = *(const float4*)&W[(size_t)(k0 + row) * N3_ + n0 + c4];
            T[c4 + 0][row] = u.x; T[c4 + 1][row] = u.y;
            T[c4 + 2][row] = u.z; T[c4 + 3][row] = u.w;
        }
        __syncthreads();
#pragma unroll
        for (int i = 0; i < 4; i++) {
            int rn = r + i * 16;
            h4 p;
            p[0] = (_Float16)T[rn][c4 + 0]; p[1] = (_Float16)T[rn][c4 + 1];
            p[2] = (_Float16)T[rn][c4 + 2]; p[3] = (_Float16)T[rn][c4 + 3];
            *(h4*)&Wt[(size_t)(n0 + rn) * E_ + k0 + c4] = p;
        }
    }
}

// ---------------- kernel 1: QKV GEMM, 32x32x16, 2-stage pipelined ----------
// BM=128, BN=192 (one head q|k|v), BK=64, wave = 64m x 96n.
// L2 remap: XCD x owns 8 heads x 8 m-blocks (A=2MB, B=3MB per XCD).
__global__ __launch_bounds__(256, 2) void qkv_gemm32(
        const _Float16* __restrict__ x16, const _Float16* __restrict__ wt,
        const float* __restrict__ bq, const float* __restrict__ w,
        _Float16* __restrict__ qws, _Float16* __restrict__ kws,
        _Float16* __restrict__ vtws) {
    __shared__ __align__(16) _Float16 Ab[2][128 * 64];   // 32 KB
    __shared__ __align__(16) _Float16 Wb[2][192 * 64];   // 48 KB

    int tid = threadIdx.x;
    int wid = tid >> 6, lane = tid & 63;
    int l31 = lane & 31, hi = lane >> 5, l7 = l31 & 7;
    int srow = lane >> 3;
    int wm = wid & 1, wn = wid >> 1;

    int L = blockIdx.x;
    int xcd = L & 7;
    int idx = L >> 3;                    // 0..63 within XCD
    int head = (xcd & 1) * 8 + (idx & 7);
    int mb   = (xcd >> 1) * 8 + (idx >> 3);
    int m0 = mb * 128;
    int n0 = head * 192;
    int b = m0 >> 11;
    int bh = b * H_ + head;
    int sblk = m0 & 2047;

    // bias folded into acc init
    fv16 acc[2][3];
#pragma unroll
    for (int ntl = 0; ntl < 3; ntl++) {
        int n_abs = wn * 96 + ntl * 32;
        int which = n_abs >> 6;
        fv16 ini;
        if (which == 2) {
            float bb = bq[n0 + n_abs + l31];
#pragma unroll
            for (int r = 0; r < 16; r++) ini[r] = bb;
        } else {
#pragma unroll
            for (int g = 0; g < 4; g++) {
                f4 bv = *(const f4*)&bq[n0 + n_abs + 8 * g + 4 * hi];
#pragma unroll
                for (int j = 0; j < 4; j++) ini[4 * g + j] = bv[j];
            }
        }
        acc[0][ntl] = ini; acc[1][ntl] = ini;
    }

    auto stage = [&](int t, int bf) {
        int k0 = t * 64;
#pragma unroll
        for (int j = 0; j < 4; j++) {
            int batch = wid * 4 + j;           // 0..15
            int row = batch * 8 + srow;
            int ch = (lane & 7) ^ srow ^ (batch & 7);
            gld16(&x16[(size_t)(m0 + row) * E_ + k0 + ch * 8], &Ab[bf][batch * 8 * 64]);
        }
#pragma unroll
        for (int j = 0; j < 6; j++) {
            int batch = wid * 6 + j;           // 0..23
            int row = batch * 8 + srow;
            int ch = (lane & 7) ^ srow ^ (batch & 7);
            gld16(&wt[(size_t)(n0 + row) * E_ + k0 + ch * 8], &Wb[bf][batch * 8 * 64]);
        }
    };

    stage(0, 0);

    for (int t = 0; t < 16; t++) {
        int bf = t & 1;
        __syncthreads();                  // drains DMA of tile t, fences buffers
        if (t < 15) stage(t + 1, bf ^ 1); // prefetch overlaps compute below
#pragma unroll
        for (int step = 0; step < 4; step++) {
            h8 af[2], wf[3];
#pragma unroll
            for (int mt = 0; mt < 2; mt++) {
                int R = wm * 64 + mt * 32 + l31;
                int ph = ((2 * step + hi) ^ l7 ^ ((mt * 4 + (l31 >> 3)) & 7)) * 8;
                af[mt] = *(const h8*)&Ab[bf][R * 64 + ph];
            }
#pragma unroll
            for (int ntl = 0; ntl < 3; ntl++) {
                int R = wn * 96 + ntl * 32 + l31;
                int ph = ((2 * step + hi) ^ l7 ^ ((wn * 12 + ntl * 4 + (l31 >> 3)) & 7)) * 8;
                wf[ntl] = *(const h8*)&Wb[bf][R * 64 + ph];
            }
#pragma unroll
            for (int ntl = 0; ntl < 3; ntl++) {
                bool isv = (wn == 1) && (ntl >= 1);
#pragma unroll
                for (int mt = 0; mt < 2; mt++) {
                    if (isv)
                        acc[mt][ntl] = __builtin_amdgcn_mfma_f32_32x32x16_f16(af[mt], wf[ntl], acc[mt][ntl], 0, 0, 0);
                    else
                        acc[mt][ntl] = __builtin_amdgcn_mfma_f32_32x32x16_f16(wf[ntl], af[mt], acc[mt][ntl], 0, 0, 0);
                }
            }
        }
    }

    // epilogue
#pragma unroll
    for (int ntl = 0; ntl < 3; ntl++) {
        int n_abs = wn * 96 + ntl * 32;
        int which = n_abs >> 6;
#pragma unroll
        for (int mt = 0; mt < 2; mt++) {
            if (which == 2) {
                // D rows = s, cols = d; V' = acc * w[s]; store Vt[d][s]
                int d = (n_abs & 63) + l31;
#pragma unroll
                for (int g = 0; g < 4; g++) {
                    int soff = wm * 64 + mt * 32 + 8 * g + 4 * hi;
                    f4 wf4 = *(const f4*)&w[m0 + soff];
                    h4 p;
#pragma unroll
                    for (int j = 0; j < 4; j++)
                        p[j] = (_Float16)(acc[mt][ntl][4 * g + j] * wf4[j]);
                    *(h4*)&vtws[((size_t)bh * 64 + d) * S_ + sblk + soff] = p;
                }
            } else {
                // D rows = d, cols = s; store [s][d]
                _Float16* dst = (which == 0) ? qws : kws;
                float scale = (which == 0) ? QSCALE : 1.0f;
                int s = sblk + wm * 64 + mt * 32 + l31;
#pragma unroll
                for (int g = 0; g < 4; g++) {
                    int d0 = (n_abs & 63) + 8 * g + 4 * hi;
                    h4 p;
#pragma unroll
                    for (int j = 0; j < 4; j++)
                        p[j] = (_Float16)(acc[mt][ntl][4 * g + j] * scale);
                    *(h4*)&dst[((size_t)bh * S_ + s) * 64 + d0] = p;
                }
            }
        }
    }
}

// ---------------- kernel 2: flash attention, in-block split-K + R5 body ----
// Block = 512 threads (8 waves), 128 q. Waves 0-3 (s=0): keys [0,1024);
// waves 4-7 (s=1): keys [1024,2048). Each wave owns 32 q (q = lane&31),
// lane-local softmax state; halves LSE-merged through LDS at the end.
// Per-tile body = R5 (best measured): w16-MFMA denominator, v_max3 tree,
// cvt_pkrtz, defer-rescale (THR=8), setprio. 16 tiles per half,
// double-buffered. LDS 68 KB -> 2 blocks/CU -> 4 waves/SIMD (2x R5 TLP).
__global__ __launch_bounds__(512, 4) void attn_kernel(
        const _Float16* __restrict__ q, const _Float16* __restrict__ k,
        const _Float16* __restrict__ vt, const _Float16* __restrict__ w16,
        float* __restrict__ out) {
    __shared__ __align__(16) _Float16 Kb[2][2][64 * 64];   // [half][buf] 32 KB
    __shared__ __align__(16) _Float16 Vb[2][2][64 * 64];   // [half][buf] 32 KB
    __shared__ __align__(16) _Float16 lws16[2048];         //  4 KB: w row (f16)

    int tid = threadIdx.x;
    int wid = tid >> 6, lane = tid & 63;
    int l31 = lane & 31, hi = lane >> 5, l7 = l31 & 7;
    int srow = lane >> 3;
    int s = wid >> 2;        // k-half
    int w4 = wid & 3;        // q-group (32 q each)
    int L = blockIdx.x;
    int bh = (L & 7) + 8 * (L >> 7);    // 16 q-tiles of a bh per XCD
    int qt = (L >> 3) & 15;
    int q0 = qt * 128;
    int b = bh >> 4, h = bh & 15;

    const _Float16* qbase = q + (size_t)bh * S_ * HD_;
    const _Float16* kbase = k + (size_t)bh * S_ * HD_;
    const _Float16* vbase = vt + (size_t)bh * HD_ * S_;
    const _Float16* wbase = w16 + (size_t)b * S_;

    // stage w row (f16, 4 KB = 4 batches; waves 0-3, wave-uniform branch)
    if (wid < 4) gld16(&wbase[wid * 512 + lane * 8], &lws16[wid * 512]);

    auto stage = [&](int t, int bf) {
        int k0 = (s * 16 + t) * 64;
#pragma unroll
        for (int j = 0; j < 2; j++) {
            int batch = w4 * 2 + j;            // 0..7 within this half's tile
            int row = batch * 8 + srow;
            int ch = l7 ^ srow ^ (batch & 7);
            gld16(&kbase[(size_t)(k0 + row) * 64 + ch * 8], &Kb[s][bf][batch * 8 * 64]);
            gld16(&vbase[(size_t)row * S_ + k0 + ch * 8], &Vb[s][bf][batch * 8 * 64]);
        }
    };

    stage(0, 0);

    int qrow = q0 + w4 * 32 + l31;
    h8 qf[4];
#pragma unroll
    for (int step = 0; step < 4; step++)
        qf[step] = *(const h8*)&qbase[(size_t)qrow * 64 + 16 * step + 8 * hi];

    fv16 o[2], ol;
    o[0] = (fv16)0.0f; o[1] = (fv16)0.0f; ol = (fv16)0.0f;
    float m_r = -INFINITY;

    for (int t = 0; t < 16; t++) {
        int bf = t & 1;
        __syncthreads();                    // drains DMA of step t
        if (t < 15) stage(t + 1, bf ^ 1);   // overlaps compute below

        // ---- S^T = K*Q^T : rows k, cols q=l31 ----
        fv16 st[2];
        st[0] = (fv16)0.0f; st[1] = (fv16)0.0f;
        __builtin_amdgcn_s_setprio(1);
#pragma unroll
        for (int step = 0; step < 4; step++) {
#pragma unroll
            for (int kt2 = 0; kt2 < 2; kt2++) {
                int R = kt2 * 32 + l31;
                int ph = ((2 * step + hi) ^ l7 ^ ((kt2 * 4 + (l31 >> 3)) & 7)) * 8;
                h8 kf = *(const h8*)&Kb[s][bf][R * 64 + ph];
                st[kt2] = __builtin_amdgcn_mfma_f32_32x32x16_f16(kf, qf[step], st[kt2], 0, 0, 0);
            }
        }
        __builtin_amdgcn_s_setprio(0);

        // ---- tree max over this lane's 32 S values (v_max3 tree) ----
        float tm[11];
#pragma unroll
        for (int r = 0; r < 10; r++)
            tm[r] = fmax3(st[(3*r)>>4][(3*r)&15], st[(3*r+1)>>4][(3*r+1)&15],
                          st[(3*r+2)>>4][(3*r+2)&15]);
        tm[10] = fmaxf(st[1][14], st[1][15]);
        float u0 = fmax3(tm[0], tm[1], tm[2]);
        float u1 = fmax3(tm[3], tm[4], tm[5]);
        float u2 = fmax3(tm[6], tm[7], tm[8]);
        float u3 = fmaxf(tm[9], tm[10]);
        float pmax = fmaxf(fmax3(u0, u1, u2), u3);

        // defer-rescale (wave-uniform branch)
        if (!__all(pmax <= m_r + RESCALE_THR)) {
            float rowmax = fmaxf(pmax, __shfl_xor(pmax, 32));
            float mnew = fmaxf(m_r, rowmax);
            float alpha = exp2_hw(m_r - mnew);   // exp2(-inf)=0 handles t=0
            m_r = mnew;
            o[0] = o[0] * alpha;
            o[1] = o[1] * alpha;
            ol = ol * alpha;
        }

        // ---- exp + packed cvt ----
        h4 pf[2][4];
#pragma unroll
        for (int kt2 = 0; kt2 < 2; kt2++)
#pragma unroll
            for (int g = 0; g < 4; g++) {
                float e0 = exp2_hw(st[kt2][4 * g + 0] - m_r);
                float e1 = exp2_hw(st[kt2][4 * g + 1] - m_r);
                float e2 = exp2_hw(st[kt2][4 * g + 2] - m_r);
                float e3 = exp2_hw(st[kt2][4 * g + 3] - m_r);
                h2 p01 = cvt_pk_f16(e0, e1);
                h2 p23 = cvt_pk_f16(e2, e3);
                h4 p;
                p[0] = p01[0]; p[1] = p01[1]; p[2] = p23[0]; p[3] = p23[1];
                pf[kt2][g] = p;
            }

        // ---- O^T += V'^T * P ; l += w-row * P (matrix pipe) ----
        int k0w = (s * 16 + t) * 64;
        __builtin_amdgcn_s_setprio(1);
#pragma unroll
        for (int kt2 = 0; kt2 < 2; kt2++)
#pragma unroll
            for (int g = 0; g < 4; g++) {
                int c = 4 * kt2 + g;
#pragma unroll
                for (int dt = 0; dt < 2; dt++) {
                    int R = dt * 32 + l31;
                    int ph = (c ^ l7 ^ ((dt * 4 + (l31 >> 3)) & 7)) * 8 + hi * 4;
                    h4 vf = *(const h4*)&Vb[s][bf][R * 64 + ph];
                    o[dt] = __builtin_amdgcn_mfma_f32_32x32x8f16(vf, pf[kt2][g], o[dt], 0, 0, 0);
                }
                h4 wf_ = *(const h4*)&lws16[k0w + c * 8 + 4 * hi];
                ol = __builtin_amdgcn_mfma_f32_32x32x8f16(wf_, pf[kt2][g], ol, 0, 0, 0);
            }
        __builtin_amdgcn_s_setprio(0);
    }

    // ---- cross-half LSE merge through LDS (reuses tile buffers) ----
    float* mO  = (float*)&Kb[0][0][0];   // [64 d][128 q] fp32 = 32 KB
    float* mML = (float*)&Vb[0][0][0];   // [128 q][m,l]
    int qloc = w4 * 32 + l31;

    __syncthreads();                     // all tile reads done; safe to overwrite
    if (s == 1) {
#pragma unroll
        for (int dt = 0; dt < 2; dt++)
#pragma unroll
            for (int r = 0; r < 16; r++) {
                int d = dt * 32 + (r & 3) + 8 * (r >> 2) + 4 * hi;
                mO[d * 128 + qloc] = o[dt][r];
            }
        if (hi == 0) {
            mML[qloc * 2]     = m_r;
            mML[qloc * 2 + 1] = ol[0];
        }
    }
    __syncthreads();
    if (s == 0) {
        float m1 = mML[qloc * 2], l1 = mML[qloc * 2 + 1];
        float mm = fmaxf(m_r, m1);
        float a0 = exp2_hw(m_r - mm), a1 = exp2_hw(m1 - mm);
        float linv = 1.0f / (ol[0] * a0 + l1 * a1);
        a0 *= linv; a1 *= linv;
        float* obase = &out[((size_t)(b * S_ + q0 + qloc)) * E_ + h * 64];
#pragma unroll
        for (int dt = 0; dt < 2; dt++)
#pragma unroll
            for (int g = 0; g < 4; g++) {
                int d0 = dt * 32 + 8 * g + 4 * hi;
                f4 ov;
#pragma unroll
                for (int j = 0; j < 4; j++)
                    ov[j] = o[dt][4 * g + j] * a0 + mO[(d0 + j) * 128 + qloc] * a1;
                *(f4*)&obase[d0] = ov;
            }
    }
}

extern "C" void kernel_launch(void* const* d_in, const int* in_sizes, int n_in,
                              void* d_out, int out_size, void* d_ws, size_t ws_size,
                              hipStream_t stream) {
    const float* x  = (const float*)d_in[0];
    const float* w  = (const float*)d_in[1];
    const float* Wq = (const float*)d_in[2];
    const float* bq = (const float*)d_in[3];
    float* out = (float*)d_out;

    char* p = (char*)d_ws;
    _Float16* x16 = (_Float16*)p;              p += (size_t)M_ * E_ * 2;
    _Float16* wt  = (_Float16*)p;              p += (size_t)E_ * N3_ * 2;
    _Float16* qb  = (_Float16*)p;              p += (size_t)M_ * E_ * 2;
    _Float16* kb  = (_Float16*)p;              p += (size_t)M_ * E_ * 2;
    _Float16* vtb = (_Float16*)p;              p += (size_t)M_ * HD_ * H_ * 2;
    _Float16* w16 = (_Float16*)p;

    prep_kernel<<<dim3(2050 + 768), dim3(256), 0, stream>>>(x, x16, w, w16, Wq, wt);
    qkv_gemm32<<<dim3(512), dim3(256), 0, stream>>>(x16, wt, bq, w, qb, kb, vtb);
    attn_kernel<<<dim3(512), dim3(512), 0, stream>>>(qb, kb, vtb, w16, out);
}

// Round 10
// 176.602 us; speedup vs baseline: 1.0646x; 1.0646x over previous
//
#include <hip/hip_runtime.h>
#include <math.h>

#define B_  2
#define S_  2048
#define E_  1024
#define H_  16
#define HD_ 64
#define N3_ 3072
#define M_  (B_*S_)   // 4096

typedef _Float16 h8  __attribute__((ext_vector_type(8)));
typedef _Float16 h4  __attribute__((ext_vector_type(4)));
typedef _Float16 h2  __attribute__((ext_vector_type(2)));
typedef __fp16   fp16x2 __attribute__((ext_vector_type(2)));
typedef float    f4  __attribute__((ext_vector_type(4)));
typedef float    fv16 __attribute__((ext_vector_type(16)));

typedef __attribute__((address_space(3))) unsigned int       lds_u32;
typedef const __attribute__((address_space(1))) unsigned int glob_u32;

// async global->LDS, 16B/lane; global addr per-lane, LDS dest = base + lane*16.
__device__ __forceinline__ void gld16(const void* g, void* l) {
    __builtin_amdgcn_global_load_lds((glob_u32*)g, (lds_u32*)l, 16, 0, 0);
}
__device__ __forceinline__ float exp2_hw(float x) { return __builtin_amdgcn_exp2f(x); }
__device__ __forceinline__ float fmax3(float a, float b, float c) {
    return fmaxf(fmaxf(a, b), c);     // fuses to v_max3_f32
}
__device__ __forceinline__ h2 cvt_pk_f16(float a, float b) {
    fp16x2 r = __builtin_amdgcn_cvt_pkrtz(a, b);
    return __builtin_bit_cast(h2, r);
}

#define QSCALE 0.18033688011112042f   // log2(e)/8
#define RESCALE_THR 8.0f              // defer-max threshold (log2 domain): P <= 2^8

// ---------------- kernel 0: fused prep ----------------
// blocks [0,2048): x fp32 -> f16 (2048 elems/block)
// blocks [2048,2050): w fp32 -> f16 (2048 elems/block)
// blocks [2050,2818): W [K][N] fp32 -> Wt [N][K] f16 (64x64 tiles)
__global__ __launch_bounds__(256) void prep_kernel(
        const float* __restrict__ x, _Float16* __restrict__ x16,
        const float* __restrict__ w, _Float16* __restrict__ w16,
        const float* __restrict__ W, _Float16* __restrict__ Wt) {
    __shared__ float T[64][65];
    int L = blockIdx.x;
    int tid = threadIdx.x;
    if (L < 2050) {
        const float* src = (L < 2048) ? &x[(size_t)L * 2048] : &w[(size_t)(L - 2048) * 2048];
        _Float16* dst    = (L < 2048) ? &x16[(size_t)L * 2048] : &w16[(size_t)(L - 2048) * 2048];
        int i = tid * 8;
        float4 u = *(const float4*)&src[i];
        float4 v = *(const float4*)&src[i + 4];
        h8 o;
        o[0] = (_Float16)u.x; o[1] = (_Float16)u.y; o[2] = (_Float16)u.z; o[3] = (_Float16)u.w;
        o[4] = (_Float16)v.x; o[5] = (_Float16)v.y; o[6] = (_Float16)v.z; o[7] = (_Float16)v.w;
        *(h8*)&dst[i] = o;
    } else {
        int L2 = L - 2050;
        int k0 = (L2 & 15) * 64, n0 = (L2 >> 4) * 64;
        int r = tid >> 4, c4 = (tid & 15) * 4;
#pragma unroll
        for (int i = 0; i < 4; i++) {
            int row = r + i * 16;
            float4 u = *(const float4*)&W[(size_t)(k0 + row) * N3_ + n0 + c4];
            T[c4 + 0][row] = u.x; T[c4 + 1][row] = u.y;
            T[c4 + 2][row] = u.z; T[c4 + 3][row] = u.w;
        }
        __syncthreads();
#pragma unroll
        for (int i = 0; i < 4; i++) {
            int rn = r + i * 16;
            h4 p;
            p[0] = (_Float16)T[rn][c4 + 0]; p[1] = (_Float16)T[rn][c4 + 1];
            p[2] = (_Float16)T[rn][c4 + 2]; p[3] = (_Float16)T[rn][c4 + 3];
            *(h4*)&Wt[(size_t)(n0 + rn) * E_ + k0 + c4] = p;
        }
    }
}

// ---------------- kernel 1: QKV GEMM, 32x32x16, counted-vmcnt pipeline ----
// BM=128, BN=192 (one head q|k|v), BK=64, wave = 64m x 96n.
// L2 remap: XCD x owns 8 heads x 8 m-blocks (A=2MB, B=3MB per XCD).
// T4 counted vmcnt: 2-deep prefetch (20 loads/wave in flight); per tile:
//   vmcnt(10) [own tile done, next tile still flying] -> s_barrier ->
//   compute -> s_barrier [WAR fence] -> stage(t+2).
// Loads never drain to 0 in the main loop (vs __syncthreads' vmcnt(0)).
__global__ __launch_bounds__(256, 2) void qkv_gemm32(
        const _Float16* __restrict__ x16, const _Float16* __restrict__ wt,
        const float* __restrict__ bq, const float* __restrict__ w,
        _Float16* __restrict__ qws, _Float16* __restrict__ kws,
        _Float16* __restrict__ vtws) {
    __shared__ __align__(16) _Float16 Ab[2][128 * 64];   // 32 KB
    __shared__ __align__(16) _Float16 Wb[2][192 * 64];   // 48 KB

    int tid = threadIdx.x;
    int wid = tid >> 6, lane = tid & 63;
    int l31 = lane & 31, hi = lane >> 5, l7 = l31 & 7;
    int srow = lane >> 3;
    int wm = wid & 1, wn = wid >> 1;

    int L = blockIdx.x;
    int xcd = L & 7;
    int idx = L >> 3;                    // 0..63 within XCD
    int head = (xcd & 1) * 8 + (idx & 7);
    int mb   = (xcd >> 1) * 8 + (idx >> 3);
    int m0 = mb * 128;
    int n0 = head * 192;
    int b = m0 >> 11;
    int bh = b * H_ + head;
    int sblk = m0 & 2047;

    // bias folded into acc init (loads consumed HERE, before the prologue
    // stages, so the compiler's waitcnt for them resolves pre-pipeline)
    fv16 acc[2][3];
#pragma unroll
    for (int ntl = 0; ntl < 3; ntl++) {
        int n_abs = wn * 96 + ntl * 32;
        int which = n_abs >> 6;
        fv16 ini;
        if (which == 2) {
            float bb = bq[n0 + n_abs + l31];
#pragma unroll
            for (int r = 0; r < 16; r++) ini[r] = bb;
        } else {
#pragma unroll
            for (int g = 0; g < 4; g++) {
                f4 bv = *(const f4*)&bq[n0 + n_abs + 8 * g + 4 * hi];
#pragma unroll
                for (int j = 0; j < 4; j++) ini[4 * g + j] = bv[j];
            }
        }
        acc[0][ntl] = ini; acc[1][ntl] = ini;
    }

    auto stage = [&](int t, int bf) {
        int k0 = t * 64;
#pragma unroll
        for (int j = 0; j < 4; j++) {
            int batch = wid * 4 + j;           // 0..15
            int row = batch * 8 + srow;
            int ch = (lane & 7) ^ srow ^ (batch & 7);
            gld16(&x16[(size_t)(m0 + row) * E_ + k0 + ch * 8], &Ab[bf][batch * 8 * 64]);
        }
#pragma unroll
        for (int j = 0; j < 6; j++) {
            int batch = wid * 6 + j;           // 0..23
            int row = batch * 8 + srow;
            int ch = (lane & 7) ^ srow ^ (batch & 7);
            gld16(&wt[(size_t)(n0 + row) * E_ + k0 + ch * 8], &Wb[bf][batch * 8 * 64]);
        }
    };

    // 2-deep prefetch prologue: 20 loads/wave in flight
    stage(0, 0);
    stage(1, 1);

    for (int t = 0; t < 16; t++) {
        int bf = t & 1;
        // own tile-t loads complete; tile-(t+1)'s 10 stay in flight
        if (t < 15) asm volatile("s_waitcnt vmcnt(10)" ::: "memory");
        else        asm volatile("s_waitcnt vmcnt(0)"  ::: "memory");
        __builtin_amdgcn_sched_barrier(0);
        __builtin_amdgcn_s_barrier();          // all waves: tile t resident
        __builtin_amdgcn_sched_barrier(0);
#pragma unroll
        for (int step = 0; step < 4; step++) {
            h8 af[2], wf[3];
#pragma unroll
            for (int mt = 0; mt < 2; mt++) {
                int R = wm * 64 + mt * 32 + l31;
                int ph = ((2 * step + hi) ^ l7 ^ ((mt * 4 + (l31 >> 3)) & 7)) * 8;
                af[mt] = *(const h8*)&Ab[bf][R * 64 + ph];
            }
#pragma unroll
            for (int ntl = 0; ntl < 3; ntl++) {
                int R = wn * 96 + ntl * 32 + l31;
                int ph = ((2 * step + hi) ^ l7 ^ ((wn * 12 + ntl * 4 + (l31 >> 3)) & 7)) * 8;
                wf[ntl] = *(const h8*)&Wb[bf][R * 64 + ph];
            }
#pragma unroll
            for (int ntl = 0; ntl < 3; ntl++) {
                bool isv = (wn == 1) && (ntl >= 1);
#pragma unroll
                for (int mt = 0; mt < 2; mt++) {
                    if (isv)
                        acc[mt][ntl] = __builtin_amdgcn_mfma_f32_32x32x16_f16(af[mt], wf[ntl], acc[mt][ntl], 0, 0, 0);
                    else
                        acc[mt][ntl] = __builtin_amdgcn_mfma_f32_32x32x16_f16(wf[ntl], af[mt], acc[mt][ntl], 0, 0, 0);
                }
            }
        }
        __builtin_amdgcn_sched_barrier(0);     // pin ds_reads above the fence
        __builtin_amdgcn_s_barrier();          // WAR fence: buf[bf] fully read
        if (t < 14) stage(t + 2, bf);          // overwrite just-freed buffer
    }

    // epilogue
#pragma unroll
    for (int ntl = 0; ntl < 3; ntl++) {
        int n_abs = wn * 96 + ntl * 32;
        int which = n_abs >> 6;
#pragma unroll
        for (int mt = 0; mt < 2; mt++) {
            if (which == 2) {
                // D rows = s, cols = d; V' = acc * w[s]; store Vt[d][s]
                int d = (n_abs & 63) + l31;
#pragma unroll
                for (int g = 0; g < 4; g++) {
                    int soff = wm * 64 + mt * 32 + 8 * g + 4 * hi;
                    f4 wf4 = *(const f4*)&w[m0 + soff];
                    h4 p;
#pragma unroll
                    for (int j = 0; j < 4; j++)
                        p[j] = (_Float16)(acc[mt][ntl][4 * g + j] * wf4[j]);
                    *(h4*)&vtws[((size_t)bh * 64 + d) * S_ + sblk + soff] = p;
                }
            } else {
                // D rows = d, cols = s; store [s][d]
                _Float16* dst = (which == 0) ? qws : kws;
                float scale = (which == 0) ? QSCALE : 1.0f;
                int s = sblk + wm * 64 + mt * 32 + l31;
#pragma unroll
                for (int g = 0; g < 4; g++) {
                    int d0 = (n_abs & 63) + 8 * g + 4 * hi;
                    h4 p;
#pragma unroll
                    for (int j = 0; j < 4; j++)
                        p[j] = (_Float16)(acc[mt][ntl][4 * g + j] * scale);
                    *(h4*)&dst[((size_t)bh * S_ + s) * 64 + d0] = p;
                }
            }
        }
    }
}

// ---------------- kernel 2: flash attention, pipelined, no P round-trip ----
// (R5 version — best measured: 67.3-67.7 us, 76 VGPR, MfmaUtil 41; parked)
// Wave = 32 q, block = 128 q, K-tile 64, 2-stage double-buffered staging.
// S^T = K*Q^T (32x32x16); P in regs; O^T = V'^T*P (32x32x8).
// q = lane&31 -> softmax state lane-local. l on matrix pipe via w16 MFMA.
// Tree max (v_max3), cvt_pkrtz, defer-rescale (THR=8), setprio.
__global__ __launch_bounds__(256, 2) void attn_kernel(
        const _Float16* __restrict__ q, const _Float16* __restrict__ k,
        const _Float16* __restrict__ vt, const _Float16* __restrict__ w16,
        float* __restrict__ out) {
    __shared__ __align__(16) _Float16 Kb[2][64 * 64];   // 16 KB
    __shared__ __align__(16) _Float16 Vb[2][64 * 64];   // 16 KB
    __shared__ __align__(16) _Float16 lws16[2048];      //  4 KB: w row (f16)

    int tid = threadIdx.x;
    int wid = tid >> 6, lane = tid & 63;
    int l31 = lane & 31, hi = lane >> 5, l7 = l31 & 7;
    int srow = lane >> 3;
    int L = blockIdx.x;
    int bh = (L & 7) + 8 * (L >> 7);    // 16 q-tiles of a bh per XCD
    int qt = (L >> 3) & 15;
    int q0 = qt * 128;
    int b = bh >> 4, h = bh & 15;

    const _Float16* qbase = q + (size_t)bh * S_ * HD_;
    const _Float16* kbase = k + (size_t)bh * S_ * HD_;
    const _Float16* vbase = vt + (size_t)bh * HD_ * S_;
    const _Float16* wbase = w16 + (size_t)b * S_;

    // stage w row (f16, 4 KB = 4 batches of 1 KB; 1 per wave, no swizzle)
    gld16(&wbase[wid * 512 + lane * 8], &lws16[wid * 512]);

    auto stage = [&](int kt, int bf) {
        int k0 = kt * 64;
#pragma unroll
        for (int j = 0; j < 2; j++) {
            int batch = wid * 2 + j;           // 0..7
            int row = batch * 8 + srow;
            int ch = (lane & 7) ^ srow ^ (batch & 7);
            gld16(&kbase[(size_t)(k0 + row) * 64 + ch * 8], &Kb[bf][batch * 8 * 64]);
            gld16(&vbase[(size_t)row * S_ + k0 + ch * 8], &Vb[bf][batch * 8 * 64]);
        }
    };

    stage(0, 0);

    int qrow = q0 + wid * 32 + l31;
    h8 qf[4];
#pragma unroll
    for (int step = 0; step < 4; step++)
        qf[step] = *(const h8*)&qbase[(size_t)qrow * 64 + 16 * step + 8 * hi];

    fv16 o[2], ol;
    o[0] = (fv16)0.0f; o[1] = (fv16)0.0f; ol = (fv16)0.0f;
    float m_r = -INFINITY;

    for (int kt = 0; kt < 32; kt++) {
        int bf = kt & 1;
        __syncthreads();                    // drains DMA of tile kt
        if (kt < 31) stage(kt + 1, bf ^ 1); // overlaps compute below

        // ---- S^T = K*Q^T : rows k, cols q=l31 ----
        fv16 st[2];
        st[0] = (fv16)0.0f; st[1] = (fv16)0.0f;
        __builtin_amdgcn_s_setprio(1);
#pragma unroll
        for (int step = 0; step < 4; step++) {
#pragma unroll
            for (int kt2 = 0; kt2 < 2; kt2++) {
                int R = kt2 * 32 + l31;
                int ph = ((2 * step + hi) ^ l7 ^ ((kt2 * 4 + (l31 >> 3)) & 7)) * 8;
                h8 kf = *(const h8*)&Kb[bf][R * 64 + ph];
                st[kt2] = __builtin_amdgcn_mfma_f32_32x32x16_f16(kf, qf[step], st[kt2], 0, 0, 0);
            }
        }
        __builtin_amdgcn_s_setprio(0);

        // ---- tree max over this lane's 32 S values (v_max3 tree) ----
        float tm[11];
#pragma unroll
        for (int r = 0; r < 10; r++)
            tm[r] = fmax3(st[(3*r)>>4][(3*r)&15], st[(3*r+1)>>4][(3*r+1)&15],
                          st[(3*r+2)>>4][(3*r+2)&15]);
        tm[10] = fmaxf(st[1][14], st[1][15]);
        float u0 = fmax3(tm[0], tm[1], tm[2]);
        float u1 = fmax3(tm[3], tm[4], tm[5]);
        float u2 = fmax3(tm[6], tm[7], tm[8]);
        float u3 = fmaxf(tm[9], tm[10]);
        float pmax = fmaxf(fmax3(u0, u1, u2), u3);

        // defer-rescale: only pay cross-lane reduce + alpha + rescale when
        // some row's max grew by more than THR (wave-uniform branch).
        if (!__all(pmax <= m_r + RESCALE_THR)) {
            float rowmax = fmaxf(pmax, __shfl_xor(pmax, 32));
            float mnew = fmaxf(m_r, rowmax);
            float alpha = exp2_hw(m_r - mnew);   // exp2(-inf)=0 handles kt=0
            m_r = mnew;
            o[0] = o[0] * alpha;
            o[1] = o[1] * alpha;
            ol = ol * alpha;
        }

        // ---- exp + packed cvt (no f32 w FMA; l goes through MFMA below) ----
        h4 pf[2][4];
#pragma unroll
        for (int kt2 = 0; kt2 < 2; kt2++)
#pragma unroll
            for (int g = 0; g < 4; g++) {
                float e0 = exp2_hw(st[kt2][4 * g + 0] - m_r);
                float e1 = exp2_hw(st[kt2][4 * g + 1] - m_r);
                float e2 = exp2_hw(st[kt2][4 * g + 2] - m_r);
                float e3 = exp2_hw(st[kt2][4 * g + 3] - m_r);
                h2 p01 = cvt_pk_f16(e0, e1);
                h2 p23 = cvt_pk_f16(e2, e3);
                h4 p;
                p[0] = p01[0]; p[1] = p01[1]; p[2] = p23[0]; p[3] = p23[1];
                pf[kt2][g] = p;
            }

        // ---- O^T += V'^T * P ; l += w-row * P (all on the matrix pipe) ----
        int k0 = kt * 64;
        __builtin_amdgcn_s_setprio(1);
#pragma unroll
        for (int kt2 = 0; kt2 < 2; kt2++)
#pragma unroll
            for (int g = 0; g < 4; g++) {
                int c = 4 * kt2 + g;
#pragma unroll
                for (int dt = 0; dt < 2; dt++) {
                    int R = dt * 32 + l31;
                    int ph = (c ^ l7 ^ ((dt * 4 + (l31 >> 3)) & 7)) * 8 + hi * 4;
                    h4 vf = *(const h4*)&Vb[bf][R * 64 + ph];
                    o[dt] = __builtin_amdgcn_mfma_f32_32x32x8f16(vf, pf[kt2][g], o[dt], 0, 0, 0);
                }
                // A = w16[k-slice] broadcast to all 32 M-rows (8B LDS
                // broadcast): every D reg = l[q=col]. Accumulates over c, kt.
                h4 wf_ = *(const h4*)&lws16[k0 + c * 8 + 4 * hi];
                ol = __builtin_amdgcn_mfma_f32_32x32x8f16(wf_, pf[kt2][g], ol, 0, 0, 0);
            }
        __builtin_amdgcn_s_setprio(0);
    }

    // ---- epilogue: l = ol[0] (valid in every lane), scale, store ----
    float linv = 1.0f / ol[0];
    float* obase = &out[((size_t)(b * S_ + qrow)) * E_ + h * 64];
#pragma unroll
    for (int dt = 0; dt < 2; dt++)
#pragma unroll
        for (int g = 0; g < 4; g++) {
            int d0 = dt * 32 + 8 * g + 4 * hi;
            f4 ov;
#pragma unroll
            for (int j = 0; j < 4; j++) ov[j] = o[dt][4 * g + j] * linv;
            *(f4*)&obase[d0] = ov;
        }
}

extern "C" void kernel_launch(void* const* d_in, const int* in_sizes, int n_in,
                              void* d_out, int out_size, void* d_ws, size_t ws_size,
                              hipStream_t stream) {
    const float* x  = (const float*)d_in[0];
    const float* w  = (const float*)d_in[1];
    const float* Wq = (const float*)d_in[2];
    const float* bq = (const float*)d_in[3];
    float* out = (float*)d_out;

    char* p = (char*)d_ws;
    _Float16* x16 = (_Float16*)p;              p += (size_t)M_ * E_ * 2;
    _Float16* wt  = (_Float16*)p;              p += (size_t)E_ * N3_ * 2;
    _Float16* qb  = (_Float16*)p;              p += (size_t)M_ * E_ * 2;
    _Float16* kb  = (_Float16*)p;              p += (size_t)M_ * E_ * 2;
    _Float16* vtb = (_Float16*)p;              p += (size_t)M_ * HD_ * H_ * 2;
    _Float16* w16 = (_Float16*)p;

    prep_kernel<<<dim3(2050 + 768), dim3(256), 0, stream>>>(x, x16, w, w16, Wq, wt);
    qkv_gemm32<<<dim3(512), dim3(256), 0, stream>>>(x16, wt, bq, w, qb, kb, vtb);
    attn_kernel<<<dim3(512), dim3(256), 0, stream>>>(qb, kb, vtb, w16, out);
}

// Round 12
// 173.195 us; speedup vs baseline: 1.0855x; 1.0197x over previous
//
#include <hip/hip_runtime.h>
#include <math.h>

#define B_  2
#define S_  2048
#define E_  1024
#define H_  16
#define HD_ 64
#define N3_ 3072
#define M_  (B_*S_)   // 4096

typedef _Float16 h8  __attribute__((ext_vector_type(8)));
typedef _Float16 h4  __attribute__((ext_vector_type(4)));
typedef _Float16 h2  __attribute__((ext_vector_type(2)));
typedef __fp16   fp16x2 __attribute__((ext_vector_type(2)));
typedef float    f4  __attribute__((ext_vector_type(4)));
typedef float    fv16 __attribute__((ext_vector_type(16)));

typedef __attribute__((address_space(3))) unsigned int       lds_u32;
typedef const __attribute__((address_space(1))) unsigned int glob_u32;

// async global->LDS, 16B/lane; global addr per-lane, LDS dest = base + lane*16.
__device__ __forceinline__ void gld16(const void* g, void* l) {
    __builtin_amdgcn_global_load_lds((glob_u32*)g, (lds_u32*)l, 16, 0, 0);
}
__device__ __forceinline__ float exp2_hw(float x) { return __builtin_amdgcn_exp2f(x); }
__device__ __forceinline__ float fmax3(float a, float b, float c) {
    return fmaxf(fmaxf(a, b), c);     // fuses to v_max3_f32
}
__device__ __forceinline__ h2 cvt_pk_f16(float a, float b) {
    fp16x2 r = __builtin_amdgcn_cvt_pkrtz(a, b);
    return __builtin_bit_cast(h2, r);
}

#define QSCALE 0.18033688011112042f   // log2(e)/8
#define RESCALE_THR 8.0f              // defer-max threshold (log2 domain): P <= 2^8

// ---------------- kernel 0: fused prep ----------------
// blocks [0,2048): x fp32 -> f16 (2048 elems/block)
// blocks [2048,2050): w fp32 -> f16 (2048 elems/block)
// blocks [2050,2818): W [K][N] fp32 -> Wt [N][K] f16 (64x64 tiles)
__global__ __launch_bounds__(256) void prep_kernel(
        const float* __restrict__ x, _Float16* __restrict__ x16,
        const float* __restrict__ w, _Float16* __restrict__ w16,
        const float* __restrict__ W, _Float16* __restrict__ Wt) {
    __shared__ float T[64][65];
    int L = blockIdx.x;
    int tid = threadIdx.x;
    if (L < 2050) {
        const float* src = (L < 2048) ? &x[(size_t)L * 2048] : &w[(size_t)(L - 2048) * 2048];
        _Float16* dst    = (L < 2048) ? &x16[(size_t)L * 2048] : &w16[(size_t)(L - 2048) * 2048];
        int i = tid * 8;
        float4 u = *(const float4*)&src[i];
        float4 v = *(const float4*)&src[i + 4];
        h8 o;
        o[0] = (_Float16)u.x; o[1] = (_Float16)u.y; o[2] = (_Float16)u.z; o[3] = (_Float16)u.w;
        o[4] = (_Float16)v.x; o[5] = (_Float16)v.y; o[6] = (_Float16)v.z; o[7] = (_Float16)v.w;
        *(h8*)&dst[i] = o;
    } else {
        int L2 = L - 2050;
        int k0 = (L2 & 15) * 64, n0 = (L2 >> 4) * 64;
        int r = tid >> 4, c4 = (tid & 15) * 4;
#pragma unroll
        for (int i = 0; i < 4; i++) {
            int row = r + i * 16;
            float4 u = *(const float4*)&W[(size_t)(k0 + row) * N3_ + n0 + c4];
            T[c4 + 0][row] = u.x; T[c4 + 1][row] = u.y;
            T[c4 + 2][row] = u.z; T[c4 + 3][row] = u.w;
        }
        __syncthreads();
#pragma unroll
        for (int i = 0; i < 4; i++) {
            int rn = r + i * 16;
            h4 p;
            p[0] = (_Float16)T[rn][c4 + 0]; p[1] = (_Float16)T[rn][c4 + 1];
            p[2] = (_Float16)T[rn][c4 + 2]; p[3] = (_Float16)T[rn][c4 + 3];
            *(h4*)&Wt[(size_t)(n0 + rn) * E_ + k0 + c4] = p;
        }
    }
}

// ---------------- kernel 1: QKV GEMM, 32x32x16, 2-stage pipelined ----------
// BM=128, BN=192 (one head q|k|v), BK=64, wave = 64m x 96n.
// L2 remap: XCD x owns 8 heads x 8 m-blocks (A=2MB, B=3MB per XCD).
__global__ __launch_bounds__(256, 2) void qkv_gemm32(
        const _Float16* __restrict__ x16, const _Float16* __restrict__ wt,
        const float* __restrict__ bq, const float* __restrict__ w,
        _Float16* __restrict__ qws, _Float16* __restrict__ kws,
        _Float16* __restrict__ vtws) {
    __shared__ __align__(16) _Float16 Ab[2][128 * 64];   // 32 KB
    __shared__ __align__(16) _Float16 Wb[2][192 * 64];   // 48 KB

    int tid = threadIdx.x;
    int wid = tid >> 6, lane = tid & 63;
    int l31 = lane & 31, hi = lane >> 5, l7 = l31 & 7;
    int srow = lane >> 3;
    int wm = wid & 1, wn = wid >> 1;

    int L = blockIdx.x;
    int xcd = L & 7;
    int idx = L >> 3;                    // 0..63 within XCD
    int head = (xcd & 1) * 8 + (idx & 7);
    int mb   = (xcd >> 1) * 8 + (idx >> 3);
    int m0 = mb * 128;
    int n0 = head * 192;
    int b = m0 >> 11;
    int bh = b * H_ + head;
    int sblk = m0 & 2047;

    // bias folded into acc init
    fv16 acc[2][3];
#pragma unroll
    for (int ntl = 0; ntl < 3; ntl++) {
        int n_abs = wn * 96 + ntl * 32;
        int which = n_abs >> 6;
        fv16 ini;
        if (which == 2) {
            float bb = bq[n0 + n_abs + l31];
#pragma unroll
            for (int r = 0; r < 16; r++) ini[r] = bb;
        } else {
#pragma unroll
            for (int g = 0; g < 4; g++) {
                f4 bv = *(const f4*)&bq[n0 + n_abs + 8 * g + 4 * hi];
#pragma unroll
                for (int j = 0; j < 4; j++) ini[4 * g + j] = bv[j];
            }
        }
        acc[0][ntl] = ini; acc[1][ntl] = ini;
    }

    auto stage = [&](int t, int bf) {
        int k0 = t * 64;
#pragma unroll
        for (int j = 0; j < 4; j++) {
            int batch = wid * 4 + j;           // 0..15
            int row = batch * 8 + srow;
            int ch = (lane & 7) ^ srow ^ (batch & 7);
            gld16(&x16[(size_t)(m0 + row) * E_ + k0 + ch * 8], &Ab[bf][batch * 8 * 64]);
        }
#pragma unroll
        for (int j = 0; j < 6; j++) {
            int batch = wid * 6 + j;           // 0..23
            int row = batch * 8 + srow;
            int ch = (lane & 7) ^ srow ^ (batch & 7);
            gld16(&wt[(size_t)(n0 + row) * E_ + k0 + ch * 8], &Wb[bf][batch * 8 * 64]);
        }
    };

    stage(0, 0);

    for (int t = 0; t < 16; t++) {
        int bf = t & 1;
        __syncthreads();                  // drains DMA of tile t, fences buffers
        if (t < 15) stage(t + 1, bf ^ 1); // prefetch overlaps compute below
#pragma unroll
        for (int step = 0; step < 4; step++) {
            h8 af[2], wf[3];
#pragma unroll
            for (int mt = 0; mt < 2; mt++) {
                int R = wm * 64 + mt * 32 + l31;
                int ph = ((2 * step + hi) ^ l7 ^ ((mt * 4 + (l31 >> 3)) & 7)) * 8;
                af[mt] = *(const h8*)&Ab[bf][R * 64 + ph];
            }
#pragma unroll
            for (int ntl = 0; ntl < 3; ntl++) {
                int R = wn * 96 + ntl * 32 + l31;
                int ph = ((2 * step + hi) ^ l7 ^ ((wn * 12 + ntl * 4 + (l31 >> 3)) & 7)) * 8;
                wf[ntl] = *(const h8*)&Wb[bf][R * 64 + ph];
            }
#pragma unroll
            for (int ntl = 0; ntl < 3; ntl++) {
                bool isv = (wn == 1) && (ntl >= 1);
#pragma unroll
                for (int mt = 0; mt < 2; mt++) {
                    if (isv)
                        acc[mt][ntl] = __builtin_amdgcn_mfma_f32_32x32x16_f16(af[mt], wf[ntl], acc[mt][ntl], 0, 0, 0);
                    else
                        acc[mt][ntl] = __builtin_amdgcn_mfma_f32_32x32x16_f16(wf[ntl], af[mt], acc[mt][ntl], 0, 0, 0);
                }
            }
        }
    }

    // epilogue
#pragma unroll
    for (int ntl = 0; ntl < 3; ntl++) {
        int n_abs = wn * 96 + ntl * 32;
        int which = n_abs >> 6;
#pragma unroll
        for (int mt = 0; mt < 2; mt++) {
            if (which == 2) {
                // D rows = s, cols = d; V' = acc * w[s]; store Vt[d][s]
                int d = (n_abs & 63) + l31;
#pragma unroll
                for (int g = 0; g < 4; g++) {
                    int soff = wm * 64 + mt * 32 + 8 * g + 4 * hi;
                    f4 wf4 = *(const f4*)&w[m0 + soff];
                    h4 p;
#pragma unroll
                    for (int j = 0; j < 4; j++)
                        p[j] = (_Float16)(acc[mt][ntl][4 * g + j] * wf4[j]);
                    *(h4*)&vtws[((size_t)bh * 64 + d) * S_ + sblk + soff] = p;
                }
            } else {
                // D rows = d, cols = s; store [s][d]
                _Float16* dst = (which == 0) ? qws : kws;
                float scale = (which == 0) ? QSCALE : 1.0f;
                int s = sblk + wm * 64 + mt * 32 + l31;
#pragma unroll
                for (int g = 0; g < 4; g++) {
                    int d0 = (n_abs & 63) + 8 * g + 4 * hi;
                    h4 p;
#pragma unroll
                    for (int j = 0; j < 4; j++)
                        p[j] = (_Float16)(acc[mt][ntl][4 * g + j] * scale);
                    *(h4*)&dst[((size_t)bh * S_ + s) * 64 + d0] = p;
                }
            }
        }
    }
}

// ---------------- kernel 2: flash attention, pipelined, no P round-trip ----
// (R5 body — best measured: 67.3-67.7 us, 76 VGPR, MfmaUtil 41-43)
// Wave = 32 q, block = 128 q, K-tile 64, 2-stage double-buffered staging.
// S^T = K*Q^T (32x32x16); P in regs; O^T = V'^T*P (32x32x8).
// q = lane&31 -> softmax state lane-local. l on matrix pipe via w16 MFMA
// (broadcast A-fragment: every D reg = l[q]); tree max (v_max3);
// cvt_pkrtz packed converts; defer-rescale (THR=8); setprio on MFMA.
__global__ __launch_bounds__(256, 2) void attn_kernel(
        const _Float16* __restrict__ q, const _Float16* __restrict__ k,
        const _Float16* __restrict__ vt, const _Float16* __restrict__ w16,
        float* __restrict__ out) {
    __shared__ __align__(16) _Float16 Kb[2][64 * 64];   // 16 KB
    __shared__ __align__(16) _Float16 Vb[2][64 * 64];   // 16 KB
    __shared__ __align__(16) _Float16 lws16[2048];      //  4 KB: w row (f16)

    int tid = threadIdx.x;
    int wid = tid >> 6, lane = tid & 63;
    int l31 = lane & 31, hi = lane >> 5, l7 = l31 & 7;
    int srow = lane >> 3;
    int L = blockIdx.x;
    int bh = (L & 7) + 8 * (L >> 7);    // 16 q-tiles of a bh per XCD
    int qt = (L >> 3) & 15;
    int q0 = qt * 128;
    int b = bh >> 4, h = bh & 15;

    const _Float16* qbase = q + (size_t)bh * S_ * HD_;
    const _Float16* kbase = k + (size_t)bh * S_ * HD_;
    const _Float16* vbase = vt + (size_t)bh * HD_ * S_;
    const _Float16* wbase = w16 + (size_t)b * S_;

    // stage w row (f16, 4 KB = 4 batches of 1 KB; 1 per wave, no swizzle)
    gld16(&wbase[wid * 512 + lane * 8], &lws16[wid * 512]);

    auto stage = [&](int kt, int bf) {
        int k0 = kt * 64;
#pragma unroll
        for (int j = 0; j < 2; j++) {
            int batch = wid * 2 + j;           // 0..7
            int row = batch * 8 + srow;
            int ch = (lane & 7) ^ srow ^ (batch & 7);
            gld16(&kbase[(size_t)(k0 + row) * 64 + ch * 8], &Kb[bf][batch * 8 * 64]);
            gld16(&vbase[(size_t)row * S_ + k0 + ch * 8], &Vb[bf][batch * 8 * 64]);
        }
    };

    stage(0, 0);

    int qrow = q0 + wid * 32 + l31;
    h8 qf[4];
#pragma unroll
    for (int step = 0; step < 4; step++)
        qf[step] = *(const h8*)&qbase[(size_t)qrow * 64 + 16 * step + 8 * hi];

    fv16 o[2], ol;
    o[0] = (fv16)0.0f; o[1] = (fv16)0.0f; ol = (fv16)0.0f;
    float m_r = -INFINITY;

    for (int kt = 0; kt < 32; kt++) {
        int bf = kt & 1;
        __syncthreads();                    // drains DMA of tile kt
        if (kt < 31) stage(kt + 1, bf ^ 1); // overlaps compute below

        // ---- S^T = K*Q^T : rows k, cols q=l31 ----
        fv16 st[2];
        st[0] = (fv16)0.0f; st[1] = (fv16)0.0f;
        __builtin_amdgcn_s_setprio(1);
#pragma unroll
        for (int step = 0; step < 4; step++) {
#pragma unroll
            for (int kt2 = 0; kt2 < 2; kt2++) {
                int R = kt2 * 32 + l31;
                int ph = ((2 * step + hi) ^ l7 ^ ((kt2 * 4 + (l31 >> 3)) & 7)) * 8;
                h8 kf = *(const h8*)&Kb[bf][R * 64 + ph];
                st[kt2] = __builtin_amdgcn_mfma_f32_32x32x16_f16(kf, qf[step], st[kt2], 0, 0, 0);
            }
        }
        __builtin_amdgcn_s_setprio(0);

        // ---- tree max over this lane's 32 S values (v_max3 tree) ----
        float tm[11];
#pragma unroll
        for (int r = 0; r < 10; r++)
            tm[r] = fmax3(st[(3*r)>>4][(3*r)&15], st[(3*r+1)>>4][(3*r+1)&15],
                          st[(3*r+2)>>4][(3*r+2)&15]);
        tm[10] = fmaxf(st[1][14], st[1][15]);
        float u0 = fmax3(tm[0], tm[1], tm[2]);
        float u1 = fmax3(tm[3], tm[4], tm[5]);
        float u2 = fmax3(tm[6], tm[7], tm[8]);
        float u3 = fmaxf(tm[9], tm[10]);
        float pmax = fmaxf(fmax3(u0, u1, u2), u3);

        // defer-rescale: only pay cross-lane reduce + alpha + rescale when
        // some row's max grew by more than THR (wave-uniform branch).
        if (!__all(pmax <= m_r + RESCALE_THR)) {
            float rowmax = fmaxf(pmax, __shfl_xor(pmax, 32));
            float mnew = fmaxf(m_r, rowmax);
            float alpha = exp2_hw(m_r - mnew);   // exp2(-inf)=0 handles kt=0
            m_r = mnew;
            o[0] = o[0] * alpha;
            o[1] = o[1] * alpha;
            ol = ol * alpha;
        }

        // ---- exp + packed cvt (no f32 w FMA; l goes through MFMA below) ----
        h4 pf[2][4];
#pragma unroll
        for (int kt2 = 0; kt2 < 2; kt2++)
#pragma unroll
            for (int g = 0; g < 4; g++) {
                float e0 = exp2_hw(st[kt2][4 * g + 0] - m_r);
                float e1 = exp2_hw(st[kt2][4 * g + 1] - m_r);
                float e2 = exp2_hw(st[kt2][4 * g + 2] - m_r);
                float e3 = exp2_hw(st[kt2][4 * g + 3] - m_r);
                h2 p01 = cvt_pk_f16(e0, e1);
                h2 p23 = cvt_pk_f16(e2, e3);
                h4 p;
                p[0] = p01[0]; p[1] = p01[1]; p[2] = p23[0]; p[3] = p23[1];
                pf[kt2][g] = p;
            }

        // ---- O^T += V'^T * P ; l += w-row * P (all on the matrix pipe) ----
        int k0 = kt * 64;
        __builtin_amdgcn_s_setprio(1);
#pragma unroll
        for (int kt2 = 0; kt2 < 2; kt2++)
#pragma unroll
            for (int g = 0; g < 4; g++) {
                int c = 4 * kt2 + g;
#pragma unroll
                for (int dt = 0; dt < 2; dt++) {
                    int R = dt * 32 + l31;
                    int ph = (c ^ l7 ^ ((dt * 4 + (l31 >> 3)) & 7)) * 8 + hi * 4;
                    h4 vf = *(const h4*)&Vb[bf][R * 64 + ph];
                    o[dt] = __builtin_amdgcn_mfma_f32_32x32x8f16(vf, pf[kt2][g], o[dt], 0, 0, 0);
                }
                // A = w16[k-slice] broadcast to all 32 M-rows (8B LDS
                // broadcast): every D reg = l[q=col]. Accumulates over c, kt.
                h4 wf_ = *(const h4*)&lws16[k0 + c * 8 + 4 * hi];
                ol = __builtin_amdgcn_mfma_f32_32x32x8f16(wf_, pf[kt2][g], ol, 0, 0, 0);
            }
        __builtin_amdgcn_s_setprio(0);
    }

    // ---- epilogue: l = ol[0] (valid in every lane), scale, store ----
    float linv = 1.0f / ol[0];
    float* obase = &out[((size_t)(b * S_ + qrow)) * E_ + h * 64];
#pragma unroll
    for (int dt = 0; dt < 2; dt++)
#pragma unroll
        for (int g = 0; g < 4; g++) {
            int d0 = dt * 32 + 8 * g + 4 * hi;
            f4 ov;
#pragma unroll
            for (int j = 0; j < 4; j++) ov[j] = o[dt][4 * g + j] * linv;
            *(f4*)&obase[d0] = ov;
        }
}

extern "C" void kernel_launch(void* const* d_in, const int* in_sizes, int n_in,
                              void* d_out, int out_size, void* d_ws, size_t ws_size,
                              hipStream_t stream) {
    const float* x  = (const float*)d_in[0];
    const float* w  = (const float*)d_in[1];
    const float* Wq = (const float*)d_in[2];
    const float* bq = (const float*)d_in[3];
    float* out = (float*)d_out;

    char* p = (char*)d_ws;
    _Float16* x16 = (_Float16*)p;              p += (size_t)M_ * E_ * 2;
    _Float16* wt  = (_Float16*)p;              p += (size_t)E_ * N3_ * 2;
    _Float16* qb  = (_Float16*)p;              p += (size_t)M_ * E_ * 2;
    _Float16* kb  = (_Float16*)p;              p += (size_t)M_ * E_ * 2;
    _Float16* vtb = (_Float16*)p;              p += (size_t)M_ * HD_ * H_ * 2;
    _Float16* w16 = (_Float16*)p;

    prep_kernel<<<dim3(2050 + 768), dim3(256), 0, stream>>>(x, x16, w, w16, Wq, wt);
    qkv_gemm32<<<dim3(512), dim3(256), 0, stream>>>(x16, wt, bq, w, qb, kb, vtb);
    attn_kernel<<<dim3(512), dim3(256), 0, stream>>>(qb, kb, vtb, w16, out);
}